// Round 6
// baseline (186.151 us; speedup 1.0000x reference)
//
#include <hip/hip_runtime.h>
#include <hip/hip_bf16.h>

#define NE 8192
#define BATCH 64
#define NNZT (NE * 32)
#define KSPLIT 4
#define KCH (NE / KSPLIT)  // 2048 k per block
#define BK 32              // k per step
#define NSTEP (KCH / BK)   // 64 steps

typedef float f32x4 __attribute__((ext_vector_type(4)));
typedef short s16x8 __attribute__((ext_vector_type(8)));

__device__ __forceinline__ unsigned short f2bf(float f) {
  unsigned u = __builtin_bit_cast(unsigned, f);
  return (unsigned short)((u + 0x7FFFu + ((u >> 16) & 1u)) >> 16);  // RNE
}

__device__ __forceinline__ s16x8 cvt8(f32x4 a, f32x4 b) {
  s16x8 r;
#pragma unroll
  for (int j = 0; j < 4; ++j) {
    r[j] = (short)f2bf(a[j]);
    r[j + 4] = (short)f2bf(b[j]);
  }
  return r;
}

// x fp32 [64][8192] -> bf16 (as ushort)
__global__ void k_convert_x(const float* __restrict__ x, unsigned short* __restrict__ xb) {
  int i = (blockIdx.x * 256 + threadIdx.x) * 4;
  float4 v = *reinterpret_cast<const float4*>(x + i);
  *reinterpret_cast<ushort4*>(xb + i) =
      make_ushort4(f2bf(v.x), f2bf(v.y), f2bf(v.z), f2bf(v.w));
}

__global__ void k_zero(float* __restrict__ p) {
  int i = (blockIdx.x * 256 + threadIdx.x) * 4;
  *reinterpret_cast<float4*>(p + i) = make_float4(0.f, 0.f, 0.f, 0.f);
}

// h = x @ W^T stored transposed ht[i][b], partial-K via atomicAdd.
// NO LDS: depth-4 register ring. Each lane loads W and x directly in MFMA
// fragment layout (lane l: row = l&15, k8 = (l>>4)*8) with plain
// global_load_dwordx4 (deep per-wave vmcnt queue, unlike the shallow
// global_load_lds DMA path measured at ~2.3 TB/s in rounds 3-5).
// Counted vmcnt(18/12/6/0) + sched_barrier fences; named slot regs (rule 20).
__global__ __launch_bounds__(256, 3) void k_dense(const unsigned short* __restrict__ xb,
                                                  const float* __restrict__ W,
                                                  float* __restrict__ ht) {
  const int tid = threadIdx.x;
  const int wave = tid >> 6, l = tid & 63;
  const int kq = blockIdx.x & (KSPLIT - 1);
  const int i0 = (blockIdx.x >> 2) * 64;
  const int k0 = kq * KCH;
  const int r = l & 15, q = l >> 4;

  // byte voffsets (32-bit) against SGPR bases
  unsigned woff = (unsigned)(((i0 + wave * 16 + r) * (size_t)NE + k0 + q * 8) * 4);
  unsigned xoff = (unsigned)((r * (size_t)NE + k0 + q * 8) * 2);
  const float* Wp = W;
  const unsigned short* xp0 = xb;
  const unsigned short* xp1 = xb + (size_t)16 * NE;
  const unsigned short* xp2 = xb + (size_t)32 * NE;
  const unsigned short* xp3 = xb + (size_t)48 * NE;

  f32x4 acc0 = {}, acc1 = {}, acc2 = {}, acc3 = {};

  // slot registers (4 slots x {2 W f32x4, 4 x s16x8})
  f32x4 w00, w01, w10, w11, w20, w21, w30, w31;
  s16x8 a00, a01, a02, a03, a10, a11, a12, a13;
  s16x8 a20, a21, a22, a23, a30, a31, a32, a33;

#define GLD0(dst, base, voff)                                              \
  asm volatile("global_load_dwordx4 %0, %1, %2 offset:0"                   \
               : "=&v"(dst) : "v"(voff), "s"(base))
#define GLD16(dst, base, voff)                                             \
  asm volatile("global_load_dwordx4 %0, %1, %2 offset:16"                  \
               : "=&v"(dst) : "v"(voff), "s"(base))

#define STAGE(W0, W1, A0, A1, A2, A3)                                      \
  do {                                                                     \
    GLD0(W0, Wp, woff);                                                    \
    GLD16(W1, Wp, woff);                                                   \
    GLD0(A0, xp0, xoff);                                                   \
    GLD0(A1, xp1, xoff);                                                   \
    GLD0(A2, xp2, xoff);                                                   \
    GLD0(A3, xp3, xoff);                                                   \
    woff += 128;                                                           \
    xoff += 64;                                                            \
  } while (0)

#define WAITI(N)                                                           \
  asm volatile("s_waitcnt vmcnt(" #N ")" ::: "memory");                    \
  __builtin_amdgcn_sched_barrier(0)

#define COMP(W0, W1, A0, A1, A2, A3)                                       \
  do {                                                                     \
    s16x8 bfr_ = cvt8(W0, W1);                                             \
    acc0 = __builtin_amdgcn_mfma_f32_16x16x32_bf16(A0, bfr_, acc0, 0, 0, 0); \
    acc1 = __builtin_amdgcn_mfma_f32_16x16x32_bf16(A1, bfr_, acc1, 0, 0, 0); \
    acc2 = __builtin_amdgcn_mfma_f32_16x16x32_bf16(A2, bfr_, acc2, 0, 0, 0); \
    acc3 = __builtin_amdgcn_mfma_f32_16x16x32_bf16(A3, bfr_, acc3, 0, 0, 0); \
    __builtin_amdgcn_sched_barrier(0);                                     \
  } while (0)

  STAGE(w00, w01, a00, a01, a02, a03);
  STAGE(w10, w11, a10, a11, a12, a13);
  STAGE(w20, w21, a20, a21, a22, a23);
  STAGE(w30, w31, a30, a31, a32, a33);

  for (int c = 0; c < NSTEP / 4 - 1; ++c) {
    WAITI(18);
    COMP(w00, w01, a00, a01, a02, a03);
    STAGE(w00, w01, a00, a01, a02, a03);
    WAITI(18);
    COMP(w10, w11, a10, a11, a12, a13);
    STAGE(w10, w11, a10, a11, a12, a13);
    WAITI(18);
    COMP(w20, w21, a20, a21, a22, a23);
    STAGE(w20, w21, a20, a21, a22, a23);
    WAITI(18);
    COMP(w30, w31, a30, a31, a32, a33);
    STAGE(w30, w31, a30, a31, a32, a33);
  }
  WAITI(18);
  COMP(w00, w01, a00, a01, a02, a03);
  WAITI(12);
  COMP(w10, w11, a10, a11, a12, a13);
  WAITI(6);
  COMP(w20, w21, a20, a21, a22, a23);
  WAITI(0);
  COMP(w30, w31, a30, a31, a32, a33);

#undef GLD0
#undef GLD16
#undef STAGE
#undef WAITI
#undef COMP

  // C/D: i = i0 + wave*16 + r (col = lane&15), b = g*16 + q*4 + j
  float* hp = ht + (size_t)(i0 + wave * 16 + r) * BATCH + q * 4;
#pragma unroll
  for (int j = 0; j < 4; ++j) atomicAdd(hp + j, acc0[j]);
#pragma unroll
  for (int j = 0; j < 4; ++j) atomicAdd(hp + 16 + j, acc1[j]);
#pragma unroll
  for (int j = 0; j < 4; ++j) atomicAdd(hp + 32 + j, acc2[j]);
#pragma unroll
  for (int j = 0; j < 4; ++j) atomicAdd(hp + 48 + j, acc3[j]);
}

// out_t[c][b] += ht[r][b] * w  for each nnz. One wave per nnz-chunk, lane = b.
__global__ void k_scatter(const float* __restrict__ ht, const float* __restrict__ sw,
                          const int* __restrict__ rows, const int* __restrict__ cols,
                          float* __restrict__ out_t) {
  const int w = (blockIdx.x * 256 + threadIdx.x) >> 6;  // 0..4095
  const int lane = threadIdx.x & 63;
  const int n0 = w * (NNZT / 4096);                     // 64 nnz per wave
#pragma unroll 4
  for (int n = n0; n < n0 + (NNZT / 4096); ++n) {
    const int r = rows[n];
    const int c = cols[n];
    const float wv = sw[n];
    atomicAdd(out_t + (size_t)c * BATCH + lane, ht[(size_t)r * BATCH + lane] * wv);
  }
}

// out[b][j] = leaky(out_t[j][b]) via LDS transpose. Grid 128 (j-tiles of 64).
__global__ void k_final(const float* __restrict__ out_t, float* __restrict__ out) {
  __shared__ float tile[64][65];
  const int t = threadIdx.x;
  const int j0 = blockIdx.x * 64;
  {
    const int jl = t >> 2, b0 = (t & 3) * 16;
    const float* src = out_t + (size_t)(j0 + jl) * BATCH + b0;
#pragma unroll
    for (int e = 0; e < 16; e += 4) {
      float4 v = *reinterpret_cast<const float4*>(src + e);
      tile[jl][b0 + e + 0] = v.x;
      tile[jl][b0 + e + 1] = v.y;
      tile[jl][b0 + e + 2] = v.z;
      tile[jl][b0 + e + 3] = v.w;
    }
  }
  __syncthreads();
  {
    const int bl = t >> 2, js = (t & 3) * 16;
    float* dst = out + (size_t)bl * NE + j0 + js;
#pragma unroll
    for (int e = 0; e < 16; e += 4) {
      float a0 = tile[js + e + 0][bl];
      float a1 = tile[js + e + 1][bl];
      float a2 = tile[js + e + 2][bl];
      float a3 = tile[js + e + 3][bl];
      float4 v;
      v.x = a0 >= 0.f ? a0 : 0.001f * a0;
      v.y = a1 >= 0.f ? a1 : 0.001f * a1;
      v.z = a2 >= 0.f ? a2 : 0.001f * a2;
      v.w = a3 >= 0.f ? a3 : 0.001f * a3;
      *reinterpret_cast<float4*>(dst + e) = v;
    }
  }
}

extern "C" void kernel_launch(void* const* d_in, const int* in_sizes, int n_in,
                              void* d_out, int out_size, void* d_ws, size_t ws_size,
                              hipStream_t stream) {
  const float* x = (const float*)d_in[0];
  const float* W = (const float*)d_in[1];
  const float* sw = (const float*)d_in[2];
  const int* idx = (const int*)d_in[3];  // [2][NNZ]: rows then cols
  float* out = (float*)d_out;

  char* ws = (char*)d_ws;
  float* ht = (float*)ws;                                   // 2 MB: ht[8192][64]
  float* out_t = (float*)(ws + (2 << 20));                  // 2 MB: out_t[8192][64]
  unsigned short* xbf = (unsigned short*)(ws + (4 << 20));  // 1 MB: x in bf16

  k_convert_x<<<512, 256, 0, stream>>>(x, xbf);
  k_zero<<<1024, 256, 0, stream>>>((float*)ws);  // zero ht + out_t (4 MB)
  k_dense<<<512, 256, 0, stream>>>(xbf, W, ht);
  k_scatter<<<1024, 256, 0, stream>>>(ht, sw, idx, idx + NNZT, out_t);
  k_final<<<128, 256, 0, stream>>>(out_t, out);
}

// Round 7
// 132.537 us; speedup vs baseline: 1.4045x; 1.4045x over previous
//
#include <hip/hip_runtime.h>
#include <hip/hip_bf16.h>

#define NE 8192
#define BATCH 64
#define NNZT (NE * 32)
#define KSPLIT 2
#define KCH (NE / KSPLIT)  // 4096 k per block
#define BK 256             // k per step
#define NSTEP (KCH / BK)   // 16 steps
#define TN 64              // W rows per block

typedef float f32x4 __attribute__((ext_vector_type(4)));
typedef short s16x8 __attribute__((ext_vector_type(8)));
typedef unsigned u32x2 __attribute__((ext_vector_type(2)));

__device__ __forceinline__ unsigned f2bf(float f) {
  unsigned u = __builtin_bit_cast(unsigned, f);
  return (u + 0x7FFFu + ((u >> 16) & 1u)) >> 16;  // RNE
}

// x fp32 [64][8192] -> bf16 (as ushort)
__global__ void k_convert_x(const float* __restrict__ x, unsigned short* __restrict__ xb) {
  int i = (blockIdx.x * 256 + threadIdx.x) * 4;
  float4 v = *reinterpret_cast<const float4*>(x + i);
  *reinterpret_cast<ushort4*>(xb + i) =
      make_ushort4((unsigned short)f2bf(v.x), (unsigned short)f2bf(v.y),
                   (unsigned short)f2bf(v.z), (unsigned short)f2bf(v.w));
}

__global__ void k_zero(float* __restrict__ p) {
  int i = (blockIdx.x * 256 + threadIdx.x) * 4;
  *reinterpret_cast<float4*>(p + i) = make_float4(0.f, 0.f, 0.f, 0.f);
}

// h = x @ W^T stored transposed ht[i][b], partial-K via atomicAdd.
// COALESCED reg-staged GEMM: every global wave-load is a contiguous
// lane-adjacent span of ONE row (W: 1 KB float4/lane; x: 512 B dwordx2/lane)
// -> memcpy-shaped requests (the only pattern measured at full read BW).
// global->reg->LDS (bf16) with XOR swizzle (row&7)<<4 on BOTH ds_write and
// ds_read. Raw s_barrier with lgkmcnt(0) only -- loads never drained; two
// register sets keep ~2 steps (96 KB/CU) in flight across barriers.
__global__ __launch_bounds__(512, 2) void k_dense(const unsigned short* __restrict__ xb,
                                                  const float* __restrict__ W,
                                                  float* __restrict__ ht) {
  __shared__ __align__(16) char smem[131072];  // [2][32K] W bf16 + [2][32K] x bf16
  const int tid = threadIdx.x;
  const int wv = tid >> 6, l = tid & 63;
  const int kq = blockIdx.x & (KSPLIT - 1);
  const int i0 = (blockIdx.x >> 1) * TN;
  const int k0 = kq * KCH;

  // staging: wave wv owns W rows wv*8..+8 and x rows wv*8..+8 per step.
  const float* wsrc = W + (size_t)(i0 + wv * 8) * NE + k0 + l * 4;          // 16 B/lane
  const unsigned short* xsrc = xb + (size_t)(wv * 8) * NE + k0 + l * 4;     // 8 B/lane
  const int swz_w = ((wv * 8) & 7) << 4;  // row&7 pattern per j handled below

  // fragment geometry (verified convention: A=x rows, B=W rows on lane&15)
  const int r16 = l & 15, q = l >> 4;
  const int wrow = (wv & 3) * 16 + r16;         // W tile row
  const int xrow0 = (wv >> 2) * 32 + r16;       // x tile row (g=0); g=1 at +16
  const int fxor = (r16 & 7) << 4;              // same for wrow/xrow0/xrow1

  f32x4 acc0 = {}, acc1 = {};
  f32x4 wrA[8], wrB[8];
  u32x2 xrA[8], xrB[8];

#define LOADW(WR, XR, s)                                                     \
  do {                                                                       \
    _Pragma("unroll") for (int j = 0; j < 8; ++j)                            \
        WR[j] = *reinterpret_cast<const f32x4*>(wsrc + (size_t)j * NE + (s) * BK); \
    _Pragma("unroll") for (int j = 0; j < 8; ++j)                            \
        XR[j] = *reinterpret_cast<const u32x2*>(xsrc + (size_t)j * NE + (s) * BK); \
    __builtin_amdgcn_sched_barrier(0);                                       \
  } while (0)

#define STORE(WR, XR, buf)                                                   \
  do {                                                                       \
    _Pragma("unroll") for (int j = 0; j < 8; ++j) {                          \
      const int r_ = wv * 8 + j;                                             \
      const int co_ = (l * 8) ^ ((r_ & 7) << 4);                             \
      u32x2 pw_;                                                             \
      pw_[0] = f2bf(WR[j][0]) | (f2bf(WR[j][1]) << 16);                      \
      pw_[1] = f2bf(WR[j][2]) | (f2bf(WR[j][3]) << 16);                      \
      *reinterpret_cast<u32x2*>(smem + (buf)*32768 + r_ * 512 + co_) = pw_;  \
      *reinterpret_cast<u32x2*>(smem + 65536 + (buf)*32768 + r_ * 512 + co_) = XR[j]; \
    }                                                                        \
    __builtin_amdgcn_sched_barrier(0);                                       \
  } while (0)

#define COMPUTE(buf)                                                         \
  do {                                                                       \
    const char* wb_ = smem + (buf)*32768 + wrow * 512;                       \
    const char* xb0_ = smem + 65536 + (buf)*32768 + xrow0 * 512;             \
    _Pragma("unroll") for (int ks = 0; ks < 8; ++ks) {                       \
      const int col_ = (ks * 64 + q * 16) ^ fxor;                            \
      s16x8 bw_ = *reinterpret_cast<const s16x8*>(wb_ + col_);               \
      s16x8 a0_ = *reinterpret_cast<const s16x8*>(xb0_ + col_);              \
      s16x8 a1_ = *reinterpret_cast<const s16x8*>(xb0_ + 8192 + col_);       \
      acc0 = __builtin_amdgcn_mfma_f32_16x16x32_bf16(a0_, bw_, acc0, 0, 0, 0); \
      acc1 = __builtin_amdgcn_mfma_f32_16x16x32_bf16(a1_, bw_, acc1, 0, 0, 0); \
    }                                                                        \
    __builtin_amdgcn_sched_barrier(0);                                       \
  } while (0)

#define SBAR()                                              \
  do {                                                      \
    asm volatile("s_waitcnt lgkmcnt(0)" ::: "memory");      \
    __builtin_amdgcn_s_barrier();                           \
    __builtin_amdgcn_sched_barrier(0);                      \
  } while (0)

  LOADW(wrA, xrA, 0);
  LOADW(wrB, xrB, 1);
  STORE(wrA, xrA, 0);
  SBAR();

  for (int s = 0; s < NSTEP; s += 2) {
    if (s + 2 < NSTEP) LOADW(wrA, xrA, s + 2);
    if (s + 1 < NSTEP) STORE(wrB, xrB, 1);
    COMPUTE(0);
    SBAR();
    if (s + 3 < NSTEP) LOADW(wrB, xrB, s + 3);
    if (s + 2 < NSTEP) STORE(wrA, xrA, 0);
    COMPUTE(1);
    SBAR();
  }

#undef LOADW
#undef STORE
#undef COMPUTE
#undef SBAR

  (void)swz_w;
  // C/D: i = i0 + (wv&3)*16 + r16 (col=lane&15), b = (wv>>2)*32 + g*16 + q*4 + j
  float* hp = ht + (size_t)(i0 + wrow) * BATCH + (wv >> 2) * 32 + q * 4;
#pragma unroll
  for (int j = 0; j < 4; ++j) atomicAdd(hp + j, acc0[j]);
#pragma unroll
  for (int j = 0; j < 4; ++j) atomicAdd(hp + 16 + j, acc1[j]);
}

// out_t[c][b] += ht[r][b] * w  for each nnz. One wave per nnz-chunk, lane = b.
__global__ void k_scatter(const float* __restrict__ ht, const float* __restrict__ sw,
                          const int* __restrict__ rows, const int* __restrict__ cols,
                          float* __restrict__ out_t) {
  const int w = (blockIdx.x * 256 + threadIdx.x) >> 6;  // 0..4095
  const int lane = threadIdx.x & 63;
  const int n0 = w * (NNZT / 4096);                     // 64 nnz per wave
#pragma unroll 4
  for (int n = n0; n < n0 + (NNZT / 4096); ++n) {
    const int r = rows[n];
    const int c = cols[n];
    const float wv = sw[n];
    atomicAdd(out_t + (size_t)c * BATCH + lane, ht[(size_t)r * BATCH + lane] * wv);
  }
}

// out[b][j] = leaky(out_t[j][b]) via LDS transpose. Grid 128 (j-tiles of 64).
__global__ void k_final(const float* __restrict__ out_t, float* __restrict__ out) {
  __shared__ float tile[64][65];
  const int t = threadIdx.x;
  const int j0 = blockIdx.x * 64;
  {
    const int jl = t >> 2, b0 = (t & 3) * 16;
    const float* src = out_t + (size_t)(j0 + jl) * BATCH + b0;
#pragma unroll
    for (int e = 0; e < 16; e += 4) {
      float4 v = *reinterpret_cast<const float4*>(src + e);
      tile[jl][b0 + e + 0] = v.x;
      tile[jl][b0 + e + 1] = v.y;
      tile[jl][b0 + e + 2] = v.z;
      tile[jl][b0 + e + 3] = v.w;
    }
  }
  __syncthreads();
  {
    const int bl = t >> 2, js = (t & 3) * 16;
    float* dst = out + (size_t)bl * NE + j0 + js;
#pragma unroll
    for (int e = 0; e < 16; e += 4) {
      float a0 = tile[js + e + 0][bl];
      float a1 = tile[js + e + 1][bl];
      float a2 = tile[js + e + 2][bl];
      float a3 = tile[js + e + 3][bl];
      float4 v;
      v.x = a0 >= 0.f ? a0 : 0.001f * a0;
      v.y = a1 >= 0.f ? a1 : 0.001f * a1;
      v.z = a2 >= 0.f ? a2 : 0.001f * a2;
      v.w = a3 >= 0.f ? a3 : 0.001f * a3;
      *reinterpret_cast<float4*>(dst + e) = v;
    }
  }
}

extern "C" void kernel_launch(void* const* d_in, const int* in_sizes, int n_in,
                              void* d_out, int out_size, void* d_ws, size_t ws_size,
                              hipStream_t stream) {
  const float* x = (const float*)d_in[0];
  const float* W = (const float*)d_in[1];
  const float* sw = (const float*)d_in[2];
  const int* idx = (const int*)d_in[3];  // [2][NNZ]: rows then cols
  float* out = (float*)d_out;

  char* ws = (char*)d_ws;
  float* ht = (float*)ws;                                   // 2 MB: ht[8192][64]
  float* out_t = (float*)(ws + (2 << 20));                  // 2 MB: out_t[8192][64]
  unsigned short* xbf = (unsigned short*)(ws + (4 << 20));  // 1 MB: x in bf16

  k_convert_x<<<512, 256, 0, stream>>>(x, xbf);
  k_zero<<<1024, 256, 0, stream>>>((float*)ws);  // zero ht + out_t (4 MB)
  k_dense<<<256, 512, 0, stream>>>(xbf, W, ht);
  k_scatter<<<1024, 256, 0, stream>>>(ht, sw, idx, idx + NNZT, out_t);
  k_final<<<128, 256, 0, stream>>>(out_t, out);
}